// Round 1
// baseline (392.731 us; speedup 1.0000x reference)
//
#include <hip/hip_runtime.h>
#include <hip/hip_bf16.h>

#define EPS 1e-8f

typedef __attribute__((ext_vector_type(8))) short short8;
typedef __attribute__((ext_vector_type(4))) float f32x4;

__device__ __forceinline__ unsigned short f2bf(float f) {
  union { float f; unsigned u; } v; v.f = f;
  unsigned r = v.u + 0x7fffu + ((v.u >> 16) & 1u);
  return (unsigned short)(r >> 16);
}
__device__ __forceinline__ float bf2f(unsigned short b) {
  union { unsigned u; float f; } v; v.u = ((unsigned)b) << 16;
  return v.f;
}

// ---------------- k0: Wg2 (512x256 f32) -> Wg2T (256x512 bf16) ----------------
__global__ __launch_bounds__(256) void k0_prep(const float* __restrict__ Wg2,
                                               unsigned short* __restrict__ Wg2T) {
  int idx = blockIdx.x * 256 + threadIdx.x;   // 131072 total
  int n = idx >> 9, k = idx & 511;
  Wg2T[n * 512 + k] = f2bf(Wg2[k * 256 + n]);
}

// ---------------- k1: h = relu(x @ We1 + be1), (4096x1024)@(1024x256) ---------
__global__ __launch_bounds__(256) void k1_enc1(const float* __restrict__ x,
                                               const float* __restrict__ We1,
                                               const float* __restrict__ be1,
                                               float* __restrict__ h) {
  __shared__ float As[16][64];
  __shared__ float Bs[64][256];
  int m0 = blockIdx.x * 16;
  int tid = threadIdx.x;
  float acc[16];
#pragma unroll
  for (int r = 0; r < 16; ++r) acc[r] = 0.f;

  for (int kc = 0; kc < 16; ++kc) {
#pragma unroll
    for (int j = 0; j < 4; ++j) {
      int e = tid + j * 256;
      int r = e >> 6, c = e & 63;
      As[r][c] = x[(m0 + r) * 1024 + kc * 64 + c];
    }
#pragma unroll
    for (int j = 0; j < 64; ++j) {
      Bs[j][tid] = We1[(kc * 64 + j) * 256 + tid];
    }
    __syncthreads();
#pragma unroll 4
    for (int k = 0; k < 64; ++k) {
      float bv = Bs[k][tid];
#pragma unroll
      for (int r = 0; r < 16; ++r) acc[r] += As[r][k] * bv;
    }
    __syncthreads();
  }
  float bias = be1[tid];
#pragma unroll
  for (int r = 0; r < 16; ++r)
    h[(m0 + r) * 256 + tid] = fmaxf(acc[r] + bias, 0.f);
}

// ---------------- k2a: z = h@We2+be2, LN over T (ddof=1), append tag ----------
__global__ __launch_bounds__(256) void k2a(const float* __restrict__ h,
                                           const float* __restrict__ We2,
                                           const float* __restrict__ be2,
                                           const float* __restrict__ gamma,
                                           const float* __restrict__ beta,
                                           float* __restrict__ zc) {
  __shared__ float hs[32][256];      // 32KB
  __shared__ float zb[32][132];      // padded
  __shared__ float We2s[128][128];   // 64KB (K-chunk of We2)
  int b = blockIdx.x, tid = threadIdx.x;

  for (int j = 0; j < 32; ++j) {
    int e = tid + j * 256;
    int t = e >> 8, c = e & 255;
    hs[t][c] = h[(b * 32 + t) * 256 + c];
  }

  float acc[16];
#pragma unroll
  for (int o = 0; o < 16; ++o) acc[o] = be2[(o * 256 + tid) & 127];

  for (int kc = 0; kc < 2; ++kc) {
    __syncthreads();
    for (int j = 0; j < 64; ++j) {
      int e = tid + j * 256;          // 16384 elems
      int k = e >> 7, zi = e & 127;
      We2s[k][zi] = We2[(kc * 128 + k) * 128 + zi];
    }
    __syncthreads();
#pragma unroll 1
    for (int o = 0; o < 16; ++o) {
      int e = o * 256 + tid;
      int t = e >> 7, zi = e & 127;
      float a = acc[o];
#pragma unroll 4
      for (int k = 0; k < 128; ++k) a += hs[t][kc * 128 + k] * We2s[k][zi];
      acc[o] = a;
    }
  }
#pragma unroll
  for (int o = 0; o < 16; ++o) {
    int e = o * 256 + tid;
    int t = e >> 7, zi = e & 127;
    zb[t][zi] = acc[o];
  }
  __syncthreads();

  if (tid < 128) {
    float s = 0.f, s2 = 0.f;
    for (int t = 0; t < 32; ++t) { float v = zb[t][tid]; s += v; s2 += v * v; }
    float mu = s * (1.f / 32.f);
    float var = (s2 - 32.f * mu * mu) * (1.f / 31.f);
    float rs = 1.f / sqrtf(fmaxf(var, 0.f) + EPS);
    float g = gamma[tid], be = beta[tid];
    for (int t = 0; t < 32; ++t)
      zb[t][tid] = (zb[t][tid] - mu) * rs * g + be;
  }
  __syncthreads();

  for (int j = 0; j < 17; ++j) {
    int e = tid + j * 256;
    if (e < 4128) {
      int t = e / 129, c = e % 129;
      zc[(b * 32 + t) * 129 + c] = (c == 128) ? (float)t : zb[t][c];
    }
  }
}

// ---------------- k2b: giA = zc@Wg1_a + bg1 ; gj = zc@Wg1_b  (bf16 out) -------
__global__ __launch_bounds__(256) void k2b(const float* __restrict__ zc,
                                           const float* __restrict__ Wg1,
                                           const float* __restrict__ bg1,
                                           unsigned short* __restrict__ giA,
                                           unsigned short* __restrict__ gj) {
  __shared__ float zs[32][132];
  int b = blockIdx.x >> 1, which = blockIdx.x & 1, tid = threadIdx.x;

  for (int j = 0; j < 17; ++j) {
    int e = tid + j * 256;
    if (e < 4128) {
      int t = e / 129, c = e % 129;
      zs[t][c] = zc[(b * 32 + t) * 129 + c];
    }
  }
  __syncthreads();

  const float* W = Wg1 + (which ? 129 * 512 : 0);
  unsigned short* out = which ? gj : giA;
  int hh0 = tid, hh1 = tid + 256;
  float accA[32], accB[32];
  float b0 = which ? 0.f : bg1[hh0];
  float b1 = which ? 0.f : bg1[hh1];
#pragma unroll
  for (int i = 0; i < 32; ++i) { accA[i] = b0; accB[i] = b1; }

  for (int c = 0; c < 129; ++c) {
    float w0 = W[c * 512 + hh0];
    float w1 = W[c * 512 + hh1];
#pragma unroll
    for (int i = 0; i < 32; ++i) {
      float v = zs[i][c];
      accA[i] += v * w0;
      accB[i] += v * w1;
    }
  }
#pragma unroll
  for (int i = 0; i < 32; ++i) {
    out[(b * 32 + i) * 512 + hh0] = f2bf(accA[i]);
    out[(b * 32 + i) * 512 + hh1] = f2bf(accB[i]);
  }
}

// ---------------- k3: all_g[b] = sum_{i,j} relu(relu(giA_i+gj_j) @ Wg2 + bg2) -
// grid: 256 = (b, col-half). 512 threads = 8 waves, wave w owns 16 cols.
// LDS: Wg2T half [128 cols][512 K] bf16 swizzled (128KB) + Htile [16][512] bf16
// swizzled (16KB). Swizzle: byte ^= (row&7)<<4 (keeps ds_read_b128 at 8-pass floor).
__global__ __launch_bounds__(512) void k3(const unsigned short* __restrict__ giA,
                                          const unsigned short* __restrict__ gj,
                                          const unsigned short* __restrict__ Wg2T,
                                          const float* __restrict__ bg2,
                                          float* __restrict__ all_g) {
  __shared__ unsigned char lds[147456];   // 128KB + 16KB
  const int HOFF = 131072;
  int b = blockIdx.x >> 1, half = blockIdx.x & 1;
  int tid = threadIdx.x;
  int lane = tid & 63, w = tid >> 6;

  // stage Wg2T half into LDS (swizzled)
  {
    const unsigned char* src = (const unsigned char*)(Wg2T + half * 128 * 512);
#pragma unroll
    for (int j = 0; j < 16; ++j) {
      int chunk = tid + j * 512;          // 8192 x 16B
      int byte = chunk * 16;
      int c = byte >> 10;
      int addr = byte ^ ((c & 7) << 4);
      short8 v = *reinterpret_cast<const short8*>(src + byte);
      *reinterpret_cast<short8*>(&lds[addr]) = v;
    }
  }
  float bias = bg2[half * 128 + w * 16 + (lane & 15)];
  float accsum = 0.f;
  __syncthreads();

  int row = lane & 15;
  int kgrp = (lane >> 4) * 8;

  for (int rf = 0; rf < 64; ++rf) {
    int ii = rf >> 1, jbase = (rf & 1) * 16;
    // H-gen: H[p][k] = relu(giA[ii][k] + gj[jbase+p][k]) as bf16, swizzled
    {
      int p = tid >> 5;                    // 0..15
      int k0 = (tid & 31) * 16;            // 16 bf16 per thread
      const unsigned short* ga = giA + ((long)(b * 32 + ii)) * 512 + k0;
      const unsigned short* gb = gj + ((long)(b * 32 + jbase + p)) * 512 + k0;
#pragma unroll
      for (int q = 0; q < 2; ++q) {
        short8 av = *reinterpret_cast<const short8*>(ga + q * 8);
        short8 bv = *reinterpret_cast<const short8*>(gb + q * 8);
        short8 hv;
#pragma unroll
        for (int e = 0; e < 8; ++e) {
          float f = bf2f((unsigned short)av[e]) + bf2f((unsigned short)bv[e]);
          hv[e] = (short)f2bf(fmaxf(f, 0.f));
        }
        int rel = p * 1024 + k0 * 2 + q * 16;
        rel ^= (p & 7) << 4;
        *reinterpret_cast<short8*>(&lds[HOFF + rel]) = hv;
      }
    }
    __syncthreads();
    // MFMA: 16 pairs x 16 cols, K=512 as 16 steps (2 interleaved chains)
    {
      f32x4 acc0 = {0.f, 0.f, 0.f, 0.f};
      f32x4 acc1 = {0.f, 0.f, 0.f, 0.f};
#pragma unroll
      for (int ks = 0; ks < 16; ++ks) {
        int ka = ks * 32 + kgrp;
        int aoff = (row * 1024 + ka * 2) ^ ((row & 7) << 4);
        int c = w * 16 + row;
        int boff = (c * 1024 + ka * 2) ^ ((c & 7) << 4);
        short8 af = *reinterpret_cast<const short8*>(&lds[HOFF + aoff]);
        short8 bfr = *reinterpret_cast<const short8*>(&lds[boff]);
        if (ks & 1)
          acc1 = __builtin_amdgcn_mfma_f32_16x16x32_bf16(af, bfr, acc1, 0, 0, 0);
        else
          acc0 = __builtin_amdgcn_mfma_f32_16x16x32_bf16(af, bfr, acc0, 0, 0, 0);
      }
#pragma unroll
      for (int r = 0; r < 4; ++r) {
        float v = acc0[r] + acc1[r] + bias;
        accsum += fmaxf(v, 0.f);
      }
    }
    __syncthreads();
  }

  accsum += __shfl_xor(accsum, 16, 64);
  accsum += __shfl_xor(accsum, 32, 64);
  if ((lane >> 4) == 0)
    all_g[b * 256 + half * 128 + w * 16 + lane] = accsum;
}

// ---------------- k4: head ----------------------------------------------------
__global__ __launch_bounds__(256) void k4(const float* __restrict__ all_g,
                                          const float* __restrict__ Wf,
                                          const float* __restrict__ bfv,
                                          const float* __restrict__ Wy,
                                          const float* __restrict__ by,
                                          float* __restrict__ out) {
  __shared__ float ag[256];
  __shared__ float fh[256];
  __shared__ float yv[4];
  int b = blockIdx.x, tid = threadIdx.x;
  ag[tid] = all_g[b * 256 + tid];
  __syncthreads();
  float a = bfv[tid];
#pragma unroll 4
  for (int k = 0; k < 256; ++k) a += ag[k] * Wf[k * 256 + tid];
  fh[tid] = fmaxf(a, 0.f);
  __syncthreads();
  if (tid < 4) {
    float y = by[tid];
    for (int k = 0; k < 256; ++k) y += fh[k] * Wy[k * 4 + tid];
    yv[tid] = y;
    out[b * 4 + tid] = y;
  }
  __syncthreads();
  if (tid == 0) {
    int am = 0;
    float best = yv[0];
    for (int o = 1; o < 4; ++o)
      if (yv[o] > best) { best = yv[o]; am = o; }
    out[512 + b] = (float)am;
  }
}

extern "C" void kernel_launch(void* const* d_in, const int* in_sizes, int n_in,
                              void* d_out, int out_size, void* d_ws, size_t ws_size,
                              hipStream_t stream) {
  const float* x     = (const float*)d_in[0];
  const float* We1   = (const float*)d_in[1];
  const float* be1   = (const float*)d_in[2];
  const float* We2   = (const float*)d_in[3];
  const float* be2   = (const float*)d_in[4];
  const float* gamma = (const float*)d_in[5];
  const float* beta  = (const float*)d_in[6];
  const float* Wg1   = (const float*)d_in[7];
  const float* bg1   = (const float*)d_in[8];
  const float* Wg2   = (const float*)d_in[9];
  const float* bg2   = (const float*)d_in[10];
  const float* Wf    = (const float*)d_in[11];
  const float* bff   = (const float*)d_in[12];
  const float* Wy    = (const float*)d_in[13];
  const float* by    = (const float*)d_in[14];

  char* ws = (char*)d_ws;
  float*          h_buf = (float*)(ws + 0);                 //  4 MB
  unsigned short* giA   = (unsigned short*)(ws + 4194304);  //  4 MB
  unsigned short* gjb   = (unsigned short*)(ws + 8388608);  //  4 MB
  unsigned short* Wg2T  = (unsigned short*)(ws + 12582912); //  256 KB
  float*          all_g = (float*)(ws + 12845056);          //  128 KB
  float*          zc    = (float*)(ws + 12976128);          // ~2 MB
  float*          out   = (float*)d_out;

  k0_prep<<<512, 256, 0, stream>>>(Wg2, Wg2T);
  k1_enc1<<<256, 256, 0, stream>>>(x, We1, be1, h_buf);
  k2a<<<128, 256, 0, stream>>>(h_buf, We2, be2, gamma, beta, zc);
  k2b<<<256, 256, 0, stream>>>(zc, Wg1, bg1, giA, gjb);
  k3<<<256, 512, 0, stream>>>(giA, gjb, Wg2T, bg2, all_g);
  k4<<<128, 256, 0, stream>>>(all_g, Wf, bff, Wy, by, out);
}

// Round 2
// 116.768 us; speedup vs baseline: 3.3634x; 3.3634x over previous
//
#include <hip/hip_runtime.h>
#include <hip/hip_bf16.h>

#define EPS 1e-8f

typedef __attribute__((ext_vector_type(8))) short short8;
typedef __attribute__((ext_vector_type(4))) float f32x4;

__device__ __forceinline__ unsigned short f2bf(float f) {
  union { float f; unsigned u; } v; v.f = f;
  unsigned r = v.u + 0x7fffu + ((v.u >> 16) & 1u);
  return (unsigned short)(r >> 16);
}
__device__ __forceinline__ float bf2f(unsigned short b) {
  union { unsigned u; float f; } v; v.u = ((unsigned)b) << 16;
  return v.f;
}
// packed f32->bf16 RTNE: dst.lo = cvt(lo), dst.hi = cvt(hi)
__device__ __forceinline__ unsigned pack_bf2(float lo, float hi) {
  unsigned r;
  asm("v_cvt_pk_bf16_f32 %0, %1, %2" : "=v"(r) : "v"(lo), "v"(hi));
  return r;
}

// ---------------- k0: build bf16 transposed weights --------------------------
// We1T [256][1024], We2T [128][256], Wg1T [1024][160] (K-pad 129->160, gi|gj), Wg2T [256][512]
__global__ __launch_bounds__(256) void k0_prep(const float* __restrict__ We1,
                                               const float* __restrict__ We2,
                                               const float* __restrict__ Wg1,
                                               const float* __restrict__ Wg2,
                                               unsigned short* __restrict__ We1T,
                                               unsigned short* __restrict__ We2T,
                                               unsigned short* __restrict__ Wg1T,
                                               unsigned short* __restrict__ Wg2T) {
  int idx = blockIdx.x * 256 + threadIdx.x;     // 589824 total
  if (idx < 262144) {
    int n = idx >> 10, k = idx & 1023;
    We1T[idx] = f2bf(We1[k * 256 + n]);
  } else if (idx < 294912) {
    int e = idx - 262144;
    int n = e >> 8, k = e & 255;
    We2T[e] = f2bf(We2[k * 128 + n]);
  } else if (idx < 458752) {
    int e = idx - 294912;
    int n = e / 160, c = e % 160;
    float v = 0.f;
    if (c < 129) v = (n < 512) ? Wg1[c * 512 + n] : Wg1[(129 + c) * 512 + (n - 512)];
    Wg1T[e] = f2bf(v);
  } else {
    int e = idx - 458752;
    int n = e >> 9, k = e & 511;
    Wg2T[e] = f2bf(Wg2[k * 256 + n]);
  }
}

// ---------------- k1: h_bf = bf16(relu(x @ We1 + be1)) -----------------------
// grid 256 (16 M-rows each), 512 thr = 8 waves x 32 cols. B in regs from We1T.
__global__ __launch_bounds__(512, 2) void k1(const float* __restrict__ x,
                                             const unsigned short* __restrict__ We1T,
                                             const float* __restrict__ be1,
                                             unsigned short* __restrict__ h_bf) {
  __shared__ unsigned char As[2][8192];   // [16][256] bf16, swizzled
  int tid = threadIdx.x, lane = tid & 63, w = tid >> 6;
  int m0 = blockIdx.x * 16;
  int srow = tid >> 5, skk = (tid & 31) * 8;
  int cb = w * 32;
  int row = lane & 15, kg = (lane >> 4) * 8;

  f32x4 acc[2] = {{0,0,0,0},{0,0,0,0}};

  auto stage = [&](int kc, int buf) {
    const float* src = x + (size_t)(m0 + srow) * 1024 + kc * 256 + skk;
    float4 a = *reinterpret_cast<const float4*>(src);
    float4 b = *reinterpret_cast<const float4*>(src + 4);
    uint4 pv;
    pv.x = pack_bf2(a.x, a.y); pv.y = pack_bf2(a.z, a.w);
    pv.z = pack_bf2(b.x, b.y); pv.w = pack_bf2(b.z, b.w);
    int addr = (srow * 512 + skk * 2) ^ ((srow & 7) << 4);
    *reinterpret_cast<uint4*>(&As[buf][addr]) = pv;
  };

  stage(0, 0);
  __syncthreads();
  for (int kc = 0; kc < 4; ++kc) {
    if (kc < 3) stage(kc + 1, (kc + 1) & 1);
    short8 breg[2][8];
#pragma unroll
    for (int cf = 0; cf < 2; ++cf)
#pragma unroll
      for (int ks = 0; ks < 8; ++ks)
        breg[cf][ks] = *reinterpret_cast<const short8*>(
            We1T + (size_t)(cb + cf * 16 + row) * 1024 + kc * 256 + ks * 32 + kg);
    const unsigned char* hc = &As[kc & 1][0];
#pragma unroll
    for (int ks = 0; ks < 8; ++ks) {
      int aoff = (row * 512 + ks * 64 + kg * 2) ^ ((row & 7) << 4);
      short8 af = *reinterpret_cast<const short8*>(hc + aoff);
      acc[0] = __builtin_amdgcn_mfma_f32_16x16x32_bf16(af, breg[0][ks], acc[0], 0, 0, 0);
      acc[1] = __builtin_amdgcn_mfma_f32_16x16x32_bf16(af, breg[1][ks], acc[1], 0, 0, 0);
    }
    __syncthreads();
  }
#pragma unroll
  for (int cf = 0; cf < 2; ++cf) {
    int col = cb + cf * 16 + row;
    float bias = be1[col];
#pragma unroll
    for (int r = 0; r < 4; ++r) {
      int orow = m0 + (lane >> 4) * 4 + r;
      h_bf[(size_t)orow * 256 + col] = f2bf(fmaxf(acc[cf][r] + bias, 0.f));
    }
  }
}

// ---------------- k2: fused z=h@We2+be2 -> LN(T) -> zc -> gi/gj = zc@Wg1T ----
// grid 128 (per b), 256 thr = 4 waves.
__global__ __launch_bounds__(256) void k2(const unsigned short* __restrict__ h_bf,
                                          const unsigned short* __restrict__ We2T,
                                          const float* __restrict__ be2,
                                          const float* __restrict__ gamma,
                                          const float* __restrict__ beta,
                                          const unsigned short* __restrict__ Wg1T,
                                          const float* __restrict__ bg1,
                                          unsigned short* __restrict__ g_all) {
  __shared__ unsigned char zcs[16384];   // [32][256] bf16 swizzled: h tile, then zc tile
  __shared__ float zb[32][132];
  int b = blockIdx.x, tid = threadIdx.x, lane = tid & 63, w = tid >> 6;
  int row = lane & 15, kg = (lane >> 4) * 8;

  // ---- phase A: stage h[b] (32x256 bf16) into LDS
  {
    int srow = tid >> 3, skk = (tid & 7) * 32;
#pragma unroll
    for (int q = 0; q < 4; ++q) {
      short8 v = *reinterpret_cast<const short8*>(
          h_bf + (size_t)(b * 32 + srow) * 256 + skk + q * 8);
      int addr = (srow * 512 + (skk + q * 8) * 2) ^ ((srow & 7) << 4);
      *reinterpret_cast<short8*>(&zcs[addr]) = v;
    }
  }
  // GEMM1 B-regs (We2T, K=256): wave w -> cols w*32..+31
  short8 breg1[2][8];
#pragma unroll
  for (int cf = 0; cf < 2; ++cf)
#pragma unroll
    for (int ks = 0; ks < 8; ++ks)
      breg1[cf][ks] = *reinterpret_cast<const short8*>(
          We2T + (size_t)(w * 32 + cf * 16 + row) * 256 + ks * 32 + kg);
  __syncthreads();

  // ---- phase B: z = h @ We2 + be2  (32x128)
  {
    f32x4 acc[2][2] = {{{0,0,0,0},{0,0,0,0}},{{0,0,0,0},{0,0,0,0}}};
#pragma unroll
    for (int ks = 0; ks < 8; ++ks) {
      int a0off = (row * 512 + ks * 64 + kg * 2) ^ ((row & 7) << 4);
      int a1off = ((16 + row) * 512 + ks * 64 + kg * 2) ^ ((row & 7) << 4);
      short8 a0 = *reinterpret_cast<const short8*>(&zcs[a0off]);
      short8 a1 = *reinterpret_cast<const short8*>(&zcs[a1off]);
#pragma unroll
      for (int cf = 0; cf < 2; ++cf) {
        acc[0][cf] = __builtin_amdgcn_mfma_f32_16x16x32_bf16(a0, breg1[cf][ks], acc[0][cf], 0, 0, 0);
        acc[1][cf] = __builtin_amdgcn_mfma_f32_16x16x32_bf16(a1, breg1[cf][ks], acc[1][cf], 0, 0, 0);
      }
    }
#pragma unroll
    for (int rf = 0; rf < 2; ++rf)
#pragma unroll
      for (int cf = 0; cf < 2; ++cf) {
        int col = w * 32 + cf * 16 + row;
        float bias = be2[col];
#pragma unroll
        for (int r = 0; r < 4; ++r)
          zb[rf * 16 + (lane >> 4) * 4 + r][col] = acc[rf][cf][r] + bias;
      }
  }
  __syncthreads();

  // ---- phase C: LayerNorm over T per col (ddof=1), write zc bf16 (+tag,+pad)
  if (tid < 128) {
    float s = 0.f, s2 = 0.f;
#pragma unroll 4
    for (int t = 0; t < 32; ++t) { float v = zb[t][tid]; s += v; s2 += v * v; }
    float mu = s * (1.f / 32.f);
    float var = (s2 - 32.f * mu * mu) * (1.f / 31.f);
    float rs = 1.f / sqrtf(fmaxf(var, 0.f) + EPS);
    float g = gamma[tid], be = beta[tid];
#pragma unroll 4
    for (int t = 0; t < 32; ++t) {
      unsigned short v = f2bf((zb[t][tid] - mu) * rs * g + be);
      int addr = (t * 512 + tid * 2) ^ ((t & 7) << 4);
      *reinterpret_cast<unsigned short*>(&zcs[addr]) = v;
    }
  } else if (tid < 160) {   // cols 128..159: tag (128) and zero-pad (129..159)
    for (int t = 0; t < 32; ++t) {
      unsigned short v = (tid == 128) ? f2bf((float)t) : 0;
      int addr = (t * 512 + tid * 2) ^ ((t & 7) << 4);
      *reinterpret_cast<unsigned short*>(&zcs[addr]) = v;
    }
  }
  __syncthreads();

  // ---- phase D: gi|gj = zc @ Wg1T  (N=1024, K=160)  wave w -> n in [w*256, w*256+256)
  {
    short8 af[2][5];
#pragma unroll
    for (int rf = 0; rf < 2; ++rf)
#pragma unroll
      for (int ks = 0; ks < 5; ++ks) {
        int aoff = ((rf * 16 + row) * 512 + ks * 64 + kg * 2) ^ ((row & 7) << 4);
        af[rf][ks] = *reinterpret_cast<const short8*>(&zcs[aoff]);
      }
#pragma unroll 1
    for (int g = 0; g < 8; ++g) {
      int n0 = w * 256 + g * 32;
      short8 bregs[2][5];
#pragma unroll
      for (int cf = 0; cf < 2; ++cf)
#pragma unroll
        for (int ks = 0; ks < 5; ++ks)
          bregs[cf][ks] = *reinterpret_cast<const short8*>(
              Wg1T + (size_t)(n0 + cf * 16 + row) * 160 + ks * 32 + kg);
      f32x4 acc[2][2] = {{{0,0,0,0},{0,0,0,0}},{{0,0,0,0},{0,0,0,0}}};
#pragma unroll
      for (int ks = 0; ks < 5; ++ks)
#pragma unroll
        for (int cf = 0; cf < 2; ++cf) {
          acc[0][cf] = __builtin_amdgcn_mfma_f32_16x16x32_bf16(af[0][ks], bregs[cf][ks], acc[0][cf], 0, 0, 0);
          acc[1][cf] = __builtin_amdgcn_mfma_f32_16x16x32_bf16(af[1][ks], bregs[cf][ks], acc[1][cf], 0, 0, 0);
        }
#pragma unroll
      for (int cf = 0; cf < 2; ++cf) {
        int n = n0 + cf * 16 + row;
        float bias = (n < 512) ? bg1[n] : 0.f;
#pragma unroll
        for (int rf = 0; rf < 2; ++rf)
#pragma unroll
          for (int r = 0; r < 4; ++r) {
            int t = rf * 16 + (lane >> 4) * 4 + r;
            g_all[((size_t)(b * 32 + t) << 10) + n] = f2bf(acc[rf][cf][r] + bias);
          }
      }
    }
  }
}

// ---------------- k3: all_gp[hi][b] = sum over (ii in half, j) of
//                  relu( relu(gi_ii + gj_j) @ Wg2 + bg2 )  -- B in registers
// grid 256 = (b, ii-half). 512 thr = 8 waves x 32 cols.
__global__ __launch_bounds__(512, 2) void k3(const unsigned short* __restrict__ g_all,
                                             const unsigned short* __restrict__ Wg2T,
                                             const float* __restrict__ bg2,
                                             float* __restrict__ all_gp) {
  __shared__ unsigned char ldsH[2][32768];   // [32][512] bf16 swizzled, dbuf
  int b = blockIdx.x >> 1, hi = blockIdx.x & 1;
  int ii0 = hi * 16;
  int tid = threadIdx.x, lane = tid & 63, w = tid >> 6;
  int row = lane & 15, kg16 = (lane >> 4) * 16;
  int cb = w * 32;
  int p = tid >> 4, kslot = tid & 15;

  // B-regs: Wg2T cols cb..cb+31, full K=512  (128 VGPR)
  short8 breg[2][16];
#pragma unroll
  for (int cf = 0; cf < 2; ++cf)
#pragma unroll
    for (int ks = 0; ks < 16; ++ks)
      breg[cf][ks] = *reinterpret_cast<const short8*>(
          Wg2T + (size_t)(cb + cf * 16 + row) * 512 + ks * 32 + (lane >> 4) * 8);

  // gj cache (fp32), thread covers row p, elements kslot*8 + q*128 + e
  float gjf[32];
  {
    const unsigned short* gjp = g_all + ((size_t)(b * 32 + p) << 10) + 512 + kslot * 8;
#pragma unroll
    for (int q = 0; q < 4; ++q) {
      short8 gv = *reinterpret_cast<const short8*>(gjp + q * 128);
#pragma unroll
      for (int e = 0; e < 8; ++e) gjf[q * 8 + e] = bf2f((unsigned short)gv[e]);
    }
  }
  float biasv[2] = { bg2[cb + row], bg2[cb + 16 + row] };
  float accsum[2] = { 0.f, 0.f };

  auto hgen = [&](int ii, int buf) {
    const unsigned short* gi = g_all + ((size_t)(b * 32 + ii) << 10) + kslot * 8;
    unsigned char* hb = &ldsH[buf][0] + p * 1024;
#pragma unroll
    for (int q = 0; q < 4; ++q) {
      short8 gv = *reinterpret_cast<const short8*>(gi + q * 128);
      uint4 pv;
      {
        float f0 = fmaxf(bf2f((unsigned short)gv[0]) + gjf[q * 8 + 0], 0.f);
        float f1 = fmaxf(bf2f((unsigned short)gv[1]) + gjf[q * 8 + 1], 0.f);
        float f2 = fmaxf(bf2f((unsigned short)gv[2]) + gjf[q * 8 + 2], 0.f);
        float f3 = fmaxf(bf2f((unsigned short)gv[3]) + gjf[q * 8 + 3], 0.f);
        float f4 = fmaxf(bf2f((unsigned short)gv[4]) + gjf[q * 8 + 4], 0.f);
        float f5 = fmaxf(bf2f((unsigned short)gv[5]) + gjf[q * 8 + 5], 0.f);
        float f6 = fmaxf(bf2f((unsigned short)gv[6]) + gjf[q * 8 + 6], 0.f);
        float f7 = fmaxf(bf2f((unsigned short)gv[7]) + gjf[q * 8 + 7], 0.f);
        pv.x = pack_bf2(f0, f1); pv.y = pack_bf2(f2, f3);
        pv.z = pack_bf2(f4, f5); pv.w = pack_bf2(f6, f7);
      }
      int addr = (kslot * 16 + q * 256) ^ ((p & 7) << 4);
      *reinterpret_cast<uint4*>(hb + addr) = pv;
    }
  };

  hgen(ii0, 0);
  __syncthreads();

  for (int it = 0; it < 16; ++it) {
    if (it < 15) hgen(ii0 + it + 1, (it + 1) & 1);
    const unsigned char* hc = &ldsH[it & 1][0];
    f32x4 acc[2][2] = {{{0,0,0,0},{0,0,0,0}},{{0,0,0,0},{0,0,0,0}}};
#pragma unroll
    for (int ks = 0; ks < 16; ++ks) {
      int a0off = (row * 1024 + ks * 64 + kg16) ^ ((row & 7) << 4);
      int a1off = ((16 + row) * 1024 + ks * 64 + kg16) ^ ((row & 7) << 4);
      short8 a0 = *reinterpret_cast<const short8*>(hc + a0off);
      short8 a1 = *reinterpret_cast<const short8*>(hc + a1off);
      acc[0][0] = __builtin_amdgcn_mfma_f32_16x16x32_bf16(a0, breg[0][ks], acc[0][0], 0, 0, 0);
      acc[0][1] = __builtin_amdgcn_mfma_f32_16x16x32_bf16(a0, breg[1][ks], acc[0][1], 0, 0, 0);
      acc[1][0] = __builtin_amdgcn_mfma_f32_16x16x32_bf16(a1, breg[0][ks], acc[1][0], 0, 0, 0);
      acc[1][1] = __builtin_amdgcn_mfma_f32_16x16x32_bf16(a1, breg[1][ks], acc[1][1], 0, 0, 0);
    }
#pragma unroll
    for (int cf = 0; cf < 2; ++cf)
#pragma unroll
      for (int rf = 0; rf < 2; ++rf)
#pragma unroll
        for (int r = 0; r < 4; ++r)
          accsum[cf] += fmaxf(acc[rf][cf][r] + biasv[cf], 0.f);
    __syncthreads();
  }

#pragma unroll
  for (int cf = 0; cf < 2; ++cf) {
    accsum[cf] += __shfl_xor(accsum[cf], 16, 64);
    accsum[cf] += __shfl_xor(accsum[cf], 32, 64);
  }
  if ((lane >> 4) == 0) {
#pragma unroll
    for (int cf = 0; cf < 2; ++cf)
      all_gp[(size_t)(hi * 128 + b) * 256 + cb + cf * 16 + lane] = accsum[cf];
  }
}

// ---------------- k4: head ----------------------------------------------------
__global__ __launch_bounds__(256) void k4(const float* __restrict__ all_gp,
                                          const float* __restrict__ Wf,
                                          const float* __restrict__ bfv,
                                          const float* __restrict__ Wy,
                                          const float* __restrict__ by,
                                          float* __restrict__ out) {
  __shared__ float ag[256];
  __shared__ float fh[256];
  __shared__ float yv[4];
  int b = blockIdx.x, tid = threadIdx.x;
  ag[tid] = all_gp[(size_t)b * 256 + tid] + all_gp[(size_t)(128 + b) * 256 + tid];
  __syncthreads();
  float a = bfv[tid];
#pragma unroll 4
  for (int k = 0; k < 256; ++k) a += ag[k] * Wf[k * 256 + tid];
  fh[tid] = fmaxf(a, 0.f);
  __syncthreads();
  if (tid < 4) {
    float y = by[tid];
    for (int k = 0; k < 256; ++k) y += fh[k] * Wy[k * 4 + tid];
    yv[tid] = y;
    out[b * 4 + tid] = y;
  }
  __syncthreads();
  if (tid == 0) {
    int am = 0;
    float best = yv[0];
    for (int o = 1; o < 4; ++o)
      if (yv[o] > best) { best = yv[o]; am = o; }
    out[512 + b] = (float)am;
  }
}

extern "C" void kernel_launch(void* const* d_in, const int* in_sizes, int n_in,
                              void* d_out, int out_size, void* d_ws, size_t ws_size,
                              hipStream_t stream) {
  const float* x     = (const float*)d_in[0];
  const float* We1   = (const float*)d_in[1];
  const float* be1   = (const float*)d_in[2];
  const float* We2   = (const float*)d_in[3];
  const float* be2   = (const float*)d_in[4];
  const float* gamma = (const float*)d_in[5];
  const float* beta  = (const float*)d_in[6];
  const float* Wg1   = (const float*)d_in[7];
  const float* bg1   = (const float*)d_in[8];
  const float* Wg2   = (const float*)d_in[9];
  const float* bg2   = (const float*)d_in[10];
  const float* Wf    = (const float*)d_in[11];
  const float* bff   = (const float*)d_in[12];
  const float* Wy    = (const float*)d_in[13];
  const float* by    = (const float*)d_in[14];

  char* ws = (char*)d_ws;
  unsigned short* h_bf  = (unsigned short*)(ws + 0);          // 2 MB
  unsigned short* g_all = (unsigned short*)(ws + 2097152);    // 8 MB  [128*32][1024] (gi|gj)
  unsigned short* We1T  = (unsigned short*)(ws + 10485760);   // 512 KB
  unsigned short* We2T  = (unsigned short*)(ws + 11010048);   // 64 KB
  unsigned short* Wg1T  = (unsigned short*)(ws + 11075584);   // 320 KB
  unsigned short* Wg2T  = (unsigned short*)(ws + 11403264);   // 256 KB
  float*          all_gp= (float*)(ws + 11665408);            // 256 KB [2][128][256]
  float*          out   = (float*)d_out;

  k0_prep<<<2304, 256, 0, stream>>>(We1, We2, Wg1, Wg2, We1T, We2T, Wg1T, Wg2T);
  k1<<<256, 512, 0, stream>>>(x, We1T, be1, h_bf);
  k2<<<128, 256, 0, stream>>>(h_bf, We2T, be2, gamma, beta, Wg1T, bg1, g_all);
  k3<<<256, 512, 0, stream>>>(g_all, Wg2T, bg2, all_gp);
  k4<<<128, 256, 0, stream>>>(all_gp, Wf, bff, Wy, by, out);
}

// Round 3
// 84.022 us; speedup vs baseline: 4.6741x; 1.3897x over previous
//
#include <hip/hip_runtime.h>
#include <hip/hip_bf16.h>

#define EPS 1e-8f

typedef __attribute__((ext_vector_type(8))) short short8;
typedef __attribute__((ext_vector_type(4))) float f32x4;

__device__ __forceinline__ unsigned short f2bf(float f) {
  union { float f; unsigned u; } v; v.f = f;
  unsigned r = v.u + 0x7fffu + ((v.u >> 16) & 1u);
  return (unsigned short)(r >> 16);
}
__device__ __forceinline__ float bf2f(unsigned short b) {
  union { unsigned u; float f; } v; v.u = ((unsigned)b) << 16;
  return v.f;
}
__device__ __forceinline__ unsigned pack_bf2(float lo, float hi) {
  unsigned r;
  asm("v_cvt_pk_bf16_f32 %0, %1, %2" : "=v"(r) : "v"(lo), "v"(hi));
  return r;
}

// ---------------- k0: build bf16 transposed weights --------------------------
// We1T [256][1024], We2T [128][256], Wg1T [1024][160], Wg2T [256][512], WfT [256][256]
__global__ __launch_bounds__(256) void k0_prep(const float* __restrict__ We1,
                                               const float* __restrict__ We2,
                                               const float* __restrict__ Wg1,
                                               const float* __restrict__ Wg2,
                                               const float* __restrict__ Wf,
                                               unsigned short* __restrict__ We1T,
                                               unsigned short* __restrict__ We2T,
                                               unsigned short* __restrict__ Wg1T,
                                               unsigned short* __restrict__ Wg2T,
                                               unsigned short* __restrict__ WfT) {
  int idx = blockIdx.x * 256 + threadIdx.x;     // 655360 total
  if (idx < 262144) {
    int n = idx >> 10, k = idx & 1023;
    We1T[idx] = f2bf(We1[k * 256 + n]);
  } else if (idx < 294912) {
    int e = idx - 262144;
    int n = e >> 8, k = e & 255;
    We2T[e] = f2bf(We2[k * 128 + n]);
  } else if (idx < 458752) {
    int e = idx - 294912;
    int n = e / 160, c = e % 160;
    float v = 0.f;
    if (c < 129) v = (n < 512) ? Wg1[c * 512 + n] : Wg1[(129 + c) * 512 + (n - 512)];
    Wg1T[e] = f2bf(v);
  } else if (idx < 589824) {
    int e = idx - 458752;
    int n = e >> 9, k = e & 511;
    Wg2T[e] = f2bf(Wg2[k * 256 + n]);
  } else {
    int e = idx - 589824;
    int n = e >> 8, k = e & 255;
    WfT[e] = f2bf(Wf[k * 256 + n]);
  }
}

// ---------------- k1: h_bf = bf16(relu(x @ We1 + be1)) -----------------------
__global__ __launch_bounds__(512, 2) void k1(const float* __restrict__ x,
                                             const unsigned short* __restrict__ We1T,
                                             const float* __restrict__ be1,
                                             unsigned short* __restrict__ h_bf) {
  __shared__ unsigned char As[2][8192];   // [16][256] bf16, swizzled
  int tid = threadIdx.x, lane = tid & 63, w = tid >> 6;
  int m0 = blockIdx.x * 16;
  int srow = tid >> 5, skk = (tid & 31) * 8;
  int cb = w * 32;
  int row = lane & 15, kg = (lane >> 4) * 8;

  f32x4 acc[2] = {{0,0,0,0},{0,0,0,0}};

  auto stage = [&](int kc, int buf) {
    const float* src = x + (size_t)(m0 + srow) * 1024 + kc * 256 + skk;
    float4 a = *reinterpret_cast<const float4*>(src);
    float4 b = *reinterpret_cast<const float4*>(src + 4);
    uint4 pv;
    pv.x = pack_bf2(a.x, a.y); pv.y = pack_bf2(a.z, a.w);
    pv.z = pack_bf2(b.x, b.y); pv.w = pack_bf2(b.z, b.w);
    int addr = (srow * 512 + skk * 2) ^ ((srow & 7) << 4);
    *reinterpret_cast<uint4*>(&As[buf][addr]) = pv;
  };

  stage(0, 0);
  __syncthreads();
  for (int kc = 0; kc < 4; ++kc) {
    if (kc < 3) stage(kc + 1, (kc + 1) & 1);
    short8 breg[2][8];
#pragma unroll
    for (int cf = 0; cf < 2; ++cf)
#pragma unroll
      for (int ks = 0; ks < 8; ++ks)
        breg[cf][ks] = *reinterpret_cast<const short8*>(
            We1T + (size_t)(cb + cf * 16 + row) * 1024 + kc * 256 + ks * 32 + kg);
    const unsigned char* hc = &As[kc & 1][0];
#pragma unroll
    for (int ks = 0; ks < 8; ++ks) {
      int aoff = (row * 512 + ks * 64 + kg * 2) ^ ((row & 7) << 4);
      short8 af = *reinterpret_cast<const short8*>(hc + aoff);
      acc[0] = __builtin_amdgcn_mfma_f32_16x16x32_bf16(af, breg[0][ks], acc[0], 0, 0, 0);
      acc[1] = __builtin_amdgcn_mfma_f32_16x16x32_bf16(af, breg[1][ks], acc[1], 0, 0, 0);
    }
    __syncthreads();
  }
#pragma unroll
  for (int cf = 0; cf < 2; ++cf) {
    int col = cb + cf * 16 + row;
    float bias = be1[col];
#pragma unroll
    for (int r = 0; r < 4; ++r) {
      int orow = m0 + (lane >> 4) * 4 + r;
      h_bf[(size_t)orow * 256 + col] = f2bf(fmaxf(acc[cf][r] + bias, 0.f));
    }
  }
}

// ---------------- k2a: z = h@We2+be2 -> LN(T, ddof=1) -> zc [4096][160] bf16 --
__global__ __launch_bounds__(256) void k2a(const unsigned short* __restrict__ h_bf,
                                           const unsigned short* __restrict__ We2T,
                                           const float* __restrict__ be2,
                                           const float* __restrict__ gamma,
                                           const float* __restrict__ beta,
                                           unsigned short* __restrict__ zc) {
  __shared__ unsigned char zcs[16384];   // [32][256] bf16 swizzled (h tile)
  __shared__ float zb[32][132];
  int b = blockIdx.x, tid = threadIdx.x, lane = tid & 63, w = tid >> 6;
  int row = lane & 15, kg = (lane >> 4) * 8;

  {
    int srow = tid >> 3, skk = (tid & 7) * 32;
#pragma unroll
    for (int q = 0; q < 4; ++q) {
      short8 v = *reinterpret_cast<const short8*>(
          h_bf + (size_t)(b * 32 + srow) * 256 + skk + q * 8);
      int addr = (srow * 512 + (skk + q * 8) * 2) ^ ((srow & 7) << 4);
      *reinterpret_cast<short8*>(&zcs[addr]) = v;
    }
  }
  short8 breg1[2][8];
#pragma unroll
  for (int cf = 0; cf < 2; ++cf)
#pragma unroll
    for (int ks = 0; ks < 8; ++ks)
      breg1[cf][ks] = *reinterpret_cast<const short8*>(
          We2T + (size_t)(w * 32 + cf * 16 + row) * 256 + ks * 32 + kg);
  __syncthreads();

  {
    f32x4 acc[2][2] = {{{0,0,0,0},{0,0,0,0}},{{0,0,0,0},{0,0,0,0}}};
#pragma unroll
    for (int ks = 0; ks < 8; ++ks) {
      int a0off = (row * 512 + ks * 64 + kg * 2) ^ ((row & 7) << 4);
      int a1off = ((16 + row) * 512 + ks * 64 + kg * 2) ^ ((row & 7) << 4);
      short8 a0 = *reinterpret_cast<const short8*>(&zcs[a0off]);
      short8 a1 = *reinterpret_cast<const short8*>(&zcs[a1off]);
#pragma unroll
      for (int cf = 0; cf < 2; ++cf) {
        acc[0][cf] = __builtin_amdgcn_mfma_f32_16x16x32_bf16(a0, breg1[cf][ks], acc[0][cf], 0, 0, 0);
        acc[1][cf] = __builtin_amdgcn_mfma_f32_16x16x32_bf16(a1, breg1[cf][ks], acc[1][cf], 0, 0, 0);
      }
    }
#pragma unroll
    for (int rf = 0; rf < 2; ++rf)
#pragma unroll
      for (int cf = 0; cf < 2; ++cf) {
        int col = w * 32 + cf * 16 + row;
        float bias = be2[col];
#pragma unroll
        for (int r = 0; r < 4; ++r)
          zb[rf * 16 + (lane >> 4) * 4 + r][col] = acc[rf][cf][r] + bias;
      }
  }
  __syncthreads();

  if (tid < 128) {
    float s = 0.f, s2 = 0.f;
#pragma unroll 4
    for (int t = 0; t < 32; ++t) { float v = zb[t][tid]; s += v; s2 += v * v; }
    float mu = s * (1.f / 32.f);
    float var = (s2 - 32.f * mu * mu) * (1.f / 31.f);
    float rs = 1.f / sqrtf(fmaxf(var, 0.f) + EPS);
    float g = gamma[tid], be = beta[tid];
#pragma unroll 4
    for (int t = 0; t < 32; ++t)
      zc[(size_t)(b * 32 + t) * 160 + tid] = f2bf((zb[t][tid] - mu) * rs * g + be);
  } else if (tid < 160) {
    for (int t = 0; t < 32; ++t)
      zc[(size_t)(b * 32 + t) * 160 + tid] = (tid == 128) ? f2bf((float)t) : 0;
  }
}

// ---------------- k2b: g_all = zc @ Wg1T (+bg1 for n<512), M=4096 N=1024 K=160
// grid 512 = (Mtile 128) x (Ntile 4), 512 thr = 8 waves x 32 cols, Mtile=32.
__global__ __launch_bounds__(512, 4) void k2b(const unsigned short* __restrict__ zc,
                                              const unsigned short* __restrict__ Wg1T,
                                              const float* __restrict__ bg1,
                                              unsigned short* __restrict__ g_all) {
  __shared__ unsigned char As[16384];   // [32][256] bf16 swizzled
  int m0 = (blockIdx.x >> 2) * 32;
  int n0 = (blockIdx.x & 3) * 256;
  int tid = threadIdx.x, lane = tid & 63, w = tid >> 6;
  int row = lane & 15, kg = (lane >> 4) * 8;
  int c0 = n0 + w * 32;

  for (int ch = tid; ch < 640; ch += 512) {
    int r = ch / 20, c16 = ch % 20;
    short8 v = *reinterpret_cast<const short8*>(zc + (size_t)(m0 + r) * 160 + c16 * 8);
    int addr = (r * 512 + c16 * 16) ^ ((r & 7) << 4);
    *reinterpret_cast<short8*>(&As[addr]) = v;
  }
  short8 breg[2][5];
#pragma unroll
  for (int cf = 0; cf < 2; ++cf)
#pragma unroll
    for (int ks = 0; ks < 5; ++ks)
      breg[cf][ks] = *reinterpret_cast<const short8*>(
          Wg1T + (size_t)(c0 + cf * 16 + row) * 160 + ks * 32 + kg);
  __syncthreads();

  f32x4 acc[2][2] = {{{0,0,0,0},{0,0,0,0}},{{0,0,0,0},{0,0,0,0}}};
#pragma unroll
  for (int ks = 0; ks < 5; ++ks) {
    int a0off = (row * 512 + ks * 64 + kg * 2) ^ ((row & 7) << 4);
    int a1off = ((16 + row) * 512 + ks * 64 + kg * 2) ^ ((row & 7) << 4);
    short8 a0 = *reinterpret_cast<const short8*>(&As[a0off]);
    short8 a1 = *reinterpret_cast<const short8*>(&As[a1off]);
#pragma unroll
    for (int cf = 0; cf < 2; ++cf) {
      acc[0][cf] = __builtin_amdgcn_mfma_f32_16x16x32_bf16(a0, breg[cf][ks], acc[0][cf], 0, 0, 0);
      acc[1][cf] = __builtin_amdgcn_mfma_f32_16x16x32_bf16(a1, breg[cf][ks], acc[1][cf], 0, 0, 0);
    }
  }
#pragma unroll
  for (int cf = 0; cf < 2; ++cf) {
    int n = c0 + cf * 16 + row;
    float bias = (n < 512) ? bg1[n] : 0.f;
#pragma unroll
    for (int rf = 0; rf < 2; ++rf)
#pragma unroll
      for (int r = 0; r < 4; ++r) {
        int mrow = m0 + rf * 16 + (lane >> 4) * 4 + r;
        g_all[((size_t)mrow << 10) + n] = f2bf(acc[rf][cf][r] + bias);
      }
  }
}

// ---------------- k3: all_gp[hi][b] = sum over (ii in half, j) --------------
__global__ __launch_bounds__(512, 2) void k3(const unsigned short* __restrict__ g_all,
                                             const unsigned short* __restrict__ Wg2T,
                                             const float* __restrict__ bg2,
                                             float* __restrict__ all_gp) {
  __shared__ unsigned char ldsH[2][32768];   // [32][512] bf16 swizzled, dbuf
  int b = blockIdx.x >> 1, hi = blockIdx.x & 1;
  int ii0 = hi * 16;
  int tid = threadIdx.x, lane = tid & 63, w = tid >> 6;
  int row = lane & 15, kg16 = (lane >> 4) * 16;
  int cb = w * 32;
  int p = tid >> 4, kslot = tid & 15;

  // B-regs: Wg2T cols cb..cb+31, full K=512  (128 VGPR)
  short8 breg[2][16];
#pragma unroll
  for (int cf = 0; cf < 2; ++cf)
#pragma unroll
    for (int ks = 0; ks < 16; ++ks)
      breg[cf][ks] = *reinterpret_cast<const short8*>(
          Wg2T + (size_t)(cb + cf * 16 + row) * 512 + ks * 32 + (lane >> 4) * 8);

  // gj cache (fp32)
  float gjf[32];
  {
    const unsigned short* gjp = g_all + ((size_t)(b * 32 + p) << 10) + 512 + kslot * 8;
#pragma unroll
    for (int q = 0; q < 4; ++q) {
      short8 gv = *reinterpret_cast<const short8*>(gjp + q * 128);
#pragma unroll
      for (int e = 0; e < 8; ++e) gjf[q * 8 + e] = bf2f((unsigned short)gv[e]);
    }
  }
  float biasv[2] = { bg2[cb + row], bg2[cb + 16 + row] };
  float accsum[2] = { 0.f, 0.f };

  short8 gv[4];   // async-STAGE: gi loads issued early, consumed after MFMA loop
  auto hload = [&](int ii) {
    const unsigned short* gi = g_all + ((size_t)(b * 32 + ii) << 10) + kslot * 8;
#pragma unroll
    for (int q = 0; q < 4; ++q)
      gv[q] = *reinterpret_cast<const short8*>(gi + q * 128);
  };
  auto hstore = [&](int buf) {
    unsigned char* hb = &ldsH[buf][0] + p * 1024;
#pragma unroll
    for (int q = 0; q < 4; ++q) {
      uint4 pv;
      float f0 = fmaxf(bf2f((unsigned short)gv[q][0]) + gjf[q * 8 + 0], 0.f);
      float f1 = fmaxf(bf2f((unsigned short)gv[q][1]) + gjf[q * 8 + 1], 0.f);
      float f2 = fmaxf(bf2f((unsigned short)gv[q][2]) + gjf[q * 8 + 2], 0.f);
      float f3 = fmaxf(bf2f((unsigned short)gv[q][3]) + gjf[q * 8 + 3], 0.f);
      float f4 = fmaxf(bf2f((unsigned short)gv[q][4]) + gjf[q * 8 + 4], 0.f);
      float f5 = fmaxf(bf2f((unsigned short)gv[q][5]) + gjf[q * 8 + 5], 0.f);
      float f6 = fmaxf(bf2f((unsigned short)gv[q][6]) + gjf[q * 8 + 6], 0.f);
      float f7 = fmaxf(bf2f((unsigned short)gv[q][7]) + gjf[q * 8 + 7], 0.f);
      pv.x = pack_bf2(f0, f1); pv.y = pack_bf2(f2, f3);
      pv.z = pack_bf2(f4, f5); pv.w = pack_bf2(f6, f7);
      int addr = (kslot * 16 + q * 256) ^ ((p & 7) << 4);
      *reinterpret_cast<uint4*>(hb + addr) = pv;
    }
  };

  hload(ii0);
  hstore(0);
  __syncthreads();

  for (int it = 0; it < 16; ++it) {
    if (it < 15) hload(ii0 + it + 1);     // issue loads; latency hides under MFMAs
    const unsigned char* hc = &ldsH[it & 1][0];
    f32x4 acc[2][2] = {{{0,0,0,0},{0,0,0,0}},{{0,0,0,0},{0,0,0,0}}};
    short8 a0 = *reinterpret_cast<const short8*>(hc + ((row * 1024 + kg16) ^ ((row & 7) << 4)));
    short8 a1 = *reinterpret_cast<const short8*>(hc + (((16 + row) * 1024 + kg16) ^ ((row & 7) << 4)));
#pragma unroll
    for (int ks = 0; ks < 16; ++ks) {
      short8 c0v = a0, c1v = a1;
      if (ks < 15) {
        a0 = *reinterpret_cast<const short8*>(hc + ((row * 1024 + (ks + 1) * 64 + kg16) ^ ((row & 7) << 4)));
        a1 = *reinterpret_cast<const short8*>(hc + (((16 + row) * 1024 + (ks + 1) * 64 + kg16) ^ ((row & 7) << 4)));
      }
      __builtin_amdgcn_s_setprio(1);
      acc[0][0] = __builtin_amdgcn_mfma_f32_16x16x32_bf16(c0v, breg[0][ks], acc[0][0], 0, 0, 0);
      acc[0][1] = __builtin_amdgcn_mfma_f32_16x16x32_bf16(c0v, breg[1][ks], acc[0][1], 0, 0, 0);
      acc[1][0] = __builtin_amdgcn_mfma_f32_16x16x32_bf16(c1v, breg[0][ks], acc[1][0], 0, 0, 0);
      acc[1][1] = __builtin_amdgcn_mfma_f32_16x16x32_bf16(c1v, breg[1][ks], acc[1][1], 0, 0, 0);
      __builtin_amdgcn_s_setprio(0);
    }
    if (it < 15) hstore((it + 1) & 1);    // consume loads after MFMAs covered latency
#pragma unroll
    for (int cf = 0; cf < 2; ++cf)
#pragma unroll
      for (int rf = 0; rf < 2; ++rf)
#pragma unroll
        for (int r = 0; r < 4; ++r)
          accsum[cf] += fmaxf(acc[rf][cf][r] + biasv[cf], 0.f);
    __syncthreads();
  }

#pragma unroll
  for (int cf = 0; cf < 2; ++cf) {
    accsum[cf] += __shfl_xor(accsum[cf], 16, 64);
    accsum[cf] += __shfl_xor(accsum[cf], 32, 64);
  }
  if ((lane >> 4) == 0) {
#pragma unroll
    for (int cf = 0; cf < 2; ++cf)
      all_gp[(size_t)(hi * 128 + b) * 256 + cb + cf * 16 + lane] = accsum[cf];
  }
}

// ---------------- k4: head (MFMA) --------------------------------------------
// grid 8 x 512thr: 16 b-rows per block. fh = relu(all_g@WfT+bf); y = fh@Wy+by.
__global__ __launch_bounds__(512) void k4(const float* __restrict__ all_gp,
                                          const unsigned short* __restrict__ WfT,
                                          const float* __restrict__ bfv,
                                          const float* __restrict__ Wy,
                                          const float* __restrict__ by,
                                          float* __restrict__ out) {
  __shared__ unsigned char As[8192];      // [16][256] bf16 swizzled
  __shared__ float fh[16][264];
  __shared__ float wys[1024];
  __shared__ float yvs[16][4];
  int tid = threadIdx.x, lane = tid & 63, w = tid >> 6;
  int row = lane & 15, kg = (lane >> 4) * 8;
  int m0 = blockIdx.x * 16;

  {
    int r = tid >> 5, c8 = (tid & 31) * 8;
    const float* p0 = all_gp + (size_t)(m0 + r) * 256 + c8;
    const float* p1 = all_gp + (size_t)(128 + m0 + r) * 256 + c8;
    float4 a0 = *reinterpret_cast<const float4*>(p0);
    float4 a1 = *reinterpret_cast<const float4*>(p0 + 4);
    float4 b0 = *reinterpret_cast<const float4*>(p1);
    float4 b1 = *reinterpret_cast<const float4*>(p1 + 4);
    uint4 pv;
    pv.x = pack_bf2(a0.x + b0.x, a0.y + b0.y);
    pv.y = pack_bf2(a0.z + b0.z, a0.w + b0.w);
    pv.z = pack_bf2(a1.x + b1.x, a1.y + b1.y);
    pv.w = pack_bf2(a1.z + b1.z, a1.w + b1.w);
    int addr = (r * 512 + c8 * 2) ^ ((r & 7) << 4);
    *reinterpret_cast<uint4*>(&As[addr]) = pv;
  }
  wys[tid] = Wy[tid];
  wys[tid + 512] = Wy[tid + 512];
  short8 breg[2][8];
#pragma unroll
  for (int cf = 0; cf < 2; ++cf)
#pragma unroll
    for (int ks = 0; ks < 8; ++ks)
      breg[cf][ks] = *reinterpret_cast<const short8*>(
          WfT + (size_t)(w * 32 + cf * 16 + row) * 256 + ks * 32 + kg);
  __syncthreads();

  f32x4 acc[2] = {{0,0,0,0},{0,0,0,0}};
#pragma unroll
  for (int ks = 0; ks < 8; ++ks) {
    int aoff = (row * 512 + ks * 64 + kg * 2) ^ ((row & 7) << 4);
    short8 af = *reinterpret_cast<const short8*>(&As[aoff]);
    acc[0] = __builtin_amdgcn_mfma_f32_16x16x32_bf16(af, breg[0][ks], acc[0], 0, 0, 0);
    acc[1] = __builtin_amdgcn_mfma_f32_16x16x32_bf16(af, breg[1][ks], acc[1], 0, 0, 0);
  }
#pragma unroll
  for (int cf = 0; cf < 2; ++cf) {
    int col = w * 32 + cf * 16 + row;
    float bias = bfv[col];
#pragma unroll
    for (int r = 0; r < 4; ++r)
      fh[(lane >> 4) * 4 + r][col] = fmaxf(acc[cf][r] + bias, 0.f);
  }
  __syncthreads();

  if (tid < 64) {
    int r = tid >> 2, o = tid & 3;
    float y = by[o];
#pragma unroll 4
    for (int k = 0; k < 256; ++k) y += fh[r][k] * wys[k * 4 + o];
    yvs[r][o] = y;
    out[(m0 + r) * 4 + o] = y;
  }
  __syncthreads();
  if (tid < 16) {
    int am = 0;
    float best = yvs[tid][0];
#pragma unroll
    for (int o = 1; o < 4; ++o)
      if (yvs[tid][o] > best) { best = yvs[tid][o]; am = o; }
    out[512 + m0 + tid] = (float)am;
  }
}

extern "C" void kernel_launch(void* const* d_in, const int* in_sizes, int n_in,
                              void* d_out, int out_size, void* d_ws, size_t ws_size,
                              hipStream_t stream) {
  const float* x     = (const float*)d_in[0];
  const float* We1   = (const float*)d_in[1];
  const float* be1   = (const float*)d_in[2];
  const float* We2   = (const float*)d_in[3];
  const float* be2   = (const float*)d_in[4];
  const float* gamma = (const float*)d_in[5];
  const float* beta  = (const float*)d_in[6];
  const float* Wg1   = (const float*)d_in[7];
  const float* bg1   = (const float*)d_in[8];
  const float* Wg2   = (const float*)d_in[9];
  const float* bg2   = (const float*)d_in[10];
  const float* Wf    = (const float*)d_in[11];
  const float* bff   = (const float*)d_in[12];
  const float* Wy    = (const float*)d_in[13];
  const float* by    = (const float*)d_in[14];

  char* ws = (char*)d_ws;
  unsigned short* h_bf  = (unsigned short*)(ws + 0);          // 2 MB
  unsigned short* g_all = (unsigned short*)(ws + 2097152);    // 8 MB
  unsigned short* We1T  = (unsigned short*)(ws + 10485760);   // 512 KB
  unsigned short* We2T  = (unsigned short*)(ws + 11010048);   // 64 KB
  unsigned short* Wg1T  = (unsigned short*)(ws + 11075584);   // 320 KB
  unsigned short* Wg2T  = (unsigned short*)(ws + 11403264);   // 256 KB
  float*          all_gp= (float*)(ws + 11665408);            // 256 KB
  unsigned short* WfT   = (unsigned short*)(ws + 11927552);   // 128 KB
  unsigned short* zc    = (unsigned short*)(ws + 12058624);   // 1.31 MB
  float*          out   = (float*)d_out;

  k0_prep<<<2560, 256, 0, stream>>>(We1, We2, Wg1, Wg2, Wf, We1T, We2T, Wg1T, Wg2T, WfT);
  k1<<<256, 512, 0, stream>>>(x, We1T, be1, h_bf);
  k2a<<<128, 256, 0, stream>>>(h_bf, We2T, be2, gamma, beta, zc);
  k2b<<<512, 512, 0, stream>>>(zc, Wg1T, bg1, g_all);
  k3<<<256, 512, 0, stream>>>(g_all, Wg2T, bg2, all_gp);
  k4<<<8, 512, 0, stream>>>(all_gp, WfT, bff, Wy, by, out);
}